// Round 1
// baseline (338.891 us; speedup 1.0000x reference)
//
#include <hip/hip_runtime.h>

#define N0 4096
#define N1 2048
#define N2 1024

// r = f + 0.2*L(f) in interior, f on boundary  (residual after jacobi-from-zero)
__device__ __forceinline__ float r_of(const float* __restrict__ f, int n, int y, int x) {
    float c = f[(size_t)y * n + x];
    if (y == 0 || y == n - 1 || x == 0 || x == n - 1) return c;
    float s = f[(size_t)(y - 1) * n + x] + f[(size_t)(y + 1) * n + x]
            + f[(size_t)y * n + x - 1] + f[(size_t)y * n + x + 1] - 4.0f * c;
    return c + 0.2f * s;
}

// fc = restrict(r(f)), fc is (nc x nc), f is (n x n), n = 2*nc
__global__ void k_res_restrict(const float* __restrict__ f, float* __restrict__ fc,
                               int n, int nc) {
    int b = blockIdx.x * blockDim.x + threadIdx.x;
    int a = blockIdx.y * blockDim.y + threadIdx.y;
    if (a >= nc || b >= nc) return;
    int y = 2 * a, x = 2 * b;
    float v = r_of(f, n, y, x) + r_of(f, n, y, x + 1)
            + r_of(f, n, y + 1, x) + r_of(f, n, y + 1, x + 1);
    fc[(size_t)a * nc + b] = 0.25f * v;
}

// v = cf*f + cs*prolong(uc)  at fine point (y,x); prolong==0 on fine boundary.
// prolong separable: even idx 2a -> 0.5*uc[a-1] + 1.5*uc[a]; odd 2a+1 -> 1.5*uc[a] + 0.5*uc[a+1]
__device__ __forceinline__ float v_of(const float* __restrict__ f, const float* __restrict__ uc,
                                      int n, int m, float cf, float cs, int y, int x) {
    float base = cf * f[(size_t)y * n + x];
    if (y == 0 || y == n - 1 || x == 0 || x == n - 1) return base;
    int a0, a1, b0, b1; float wr0, wr1, wc0, wc1;
    if (y & 1) { a0 = y >> 1; a1 = a0 + 1; wr0 = 1.5f; wr1 = 0.5f; }
    else       { a1 = y >> 1; a0 = a1 - 1; wr0 = 0.5f; wr1 = 1.5f; }
    if (x & 1) { b0 = x >> 1; b1 = b0 + 1; wc0 = 1.5f; wc1 = 0.5f; }
    else       { b1 = x >> 1; b0 = b1 - 1; wc0 = 0.5f; wc1 = 1.5f; }
    float p = wr0 * (wc0 * uc[(size_t)a0 * m + b0] + wc1 * uc[(size_t)a0 * m + b1])
            + wr1 * (wc0 * uc[(size_t)a1 * m + b0] + wc1 * uc[(size_t)a1 * m + b1]);
    return base + cs * p;
}

// u = jacobi(v, f):  interior u = v + cf*f + 0.2*L(v);  boundary u = v + cf*f
__global__ void k_correct_smooth(const float* __restrict__ f, const float* __restrict__ uc,
                                 float* __restrict__ u, int n, int m, float cf, float cs) {
    int x = blockIdx.x * blockDim.x + threadIdx.x;
    int y = blockIdx.y * blockDim.y + threadIdx.y;
    if (x >= n || y >= n) return;
    float vc  = v_of(f, uc, n, m, cf, cs, y, x);
    float fij = f[(size_t)y * n + x];
    float out;
    if (y == 0 || y == n - 1 || x == 0 || x == n - 1) {
        out = vc + cf * fij;
    } else {
        float vu = v_of(f, uc, n, m, cf, cs, y - 1, x);
        float vd = v_of(f, uc, n, m, cf, cs, y + 1, x);
        float vl = v_of(f, uc, n, m, cf, cs, y, x - 1);
        float vr = v_of(f, uc, n, m, cf, cs, y, x + 1);
        out = vc + cf * fij + 0.2f * (vu + vd + vl + vr - 4.0f * vc);
    }
    u[(size_t)y * n + x] = out;
}

// per-block partial sums of |f - A(u)| and |f|
__global__ void k_resid_sums(const float* __restrict__ f, const float* __restrict__ u,
                             double* __restrict__ pT, double* __restrict__ pF, int n) {
    int x = blockIdx.x * blockDim.x + threadIdx.x;
    int y = blockIdx.y * blockDim.y + threadIdx.y;
    float t = 0.0f, af = 0.0f;
    if (x < n && y < n) {
        float fij = f[(size_t)y * n + x];
        af = fabsf(fij);
        if (y == 0 || y == n - 1 || x == 0 || x == n - 1) {
            t = fabsf(fij);
        } else {
            float L = u[(size_t)(y - 1) * n + x] + u[(size_t)(y + 1) * n + x]
                    + u[(size_t)y * n + x - 1] + u[(size_t)y * n + x + 1]
                    - 4.0f * u[(size_t)y * n + x];
            t = fabsf(fij - (float)n * (float)n * L);
        }
    }
    __shared__ double sT[256], sF[256];
    int tid = threadIdx.y * blockDim.x + threadIdx.x;
    sT[tid] = (double)t; sF[tid] = (double)af;
    __syncthreads();
    for (int s = 128; s > 0; s >>= 1) {
        if (tid < s) { sT[tid] += sT[tid + s]; sF[tid] += sF[tid + s]; }
        __syncthreads();
    }
    if (tid == 0) {
        int bid = blockIdx.y * gridDim.x + blockIdx.x;
        pT[bid] = sT[0];
        pF[bid] = sF[0];
    }
}

__global__ void k_final(const double* __restrict__ pT, const double* __restrict__ pF,
                        int nb, float* __restrict__ out_res) {
    __shared__ double sT[256], sF[256];
    double tT = 0.0, tF = 0.0;
    for (int i = threadIdx.x; i < nb; i += 256) { tT += pT[i]; tF += pF[i]; }
    sT[threadIdx.x] = tT; sF[threadIdx.x] = tF;
    __syncthreads();
    for (int s = 128; s > 0; s >>= 1) {
        if (threadIdx.x < s) { sT[threadIdx.x] += sT[threadIdx.x + s]; sF[threadIdx.x] += sF[threadIdx.x + s]; }
        __syncthreads();
    }
    if (threadIdx.x == 0) *out_res = (float)(sT[0] / sF[0]);
}

extern "C" void kernel_launch(void* const* d_in, const int* in_sizes, int n_in,
                              void* d_out, int out_size, void* d_ws, size_t ws_size,
                              hipStream_t stream) {
    const float* f0 = (const float*)d_in[0];
    float* u0  = (float*)d_out;                      // N0*N0 floats
    float* res = u0 + (size_t)N0 * N0;               // scalar

    char* ws = (char*)d_ws;
    float* f1 = (float*)ws;                                           // N1*N1
    float* u1 = (float*)(ws + (size_t)N1 * N1 * 4);                   // N1*N1
    float* f2 = (float*)(ws + (size_t)2 * N1 * N1 * 4);               // N2*N2
    double* pT = (double*)(ws + (size_t)2 * N1 * N1 * 4 + (size_t)N2 * N2 * 4);
    double* pF = pT + 65536;

    const float c0 = -0.2f / ((float)N0 * (float)N0);
    const float c1 = -0.2f / ((float)N1 * (float)N1);
    const float c2 = -0.2f / ((float)N2 * (float)N2);

    dim3 blk(16, 16);
    // level 0 -> f1
    k_res_restrict<<<dim3(N1 / 16, N1 / 16), blk, 0, stream>>>(f0, f1, N0, N1);
    // level 1 -> f2
    k_res_restrict<<<dim3(N2 / 16, N2 / 16), blk, 0, stream>>>(f1, f2, N1, N2);
    // u1 = jacobi(c1*f1 + prolong(c2*f2), f1)
    k_correct_smooth<<<dim3(N1 / 16, N1 / 16), blk, 0, stream>>>(f1, f2, u1, N1, N2, c1, c2);
    // u0 = jacobi(c0*f0 + prolong(u1), f0)
    k_correct_smooth<<<dim3(N0 / 16, N0 / 16), blk, 0, stream>>>(f0, u1, u0, N0, N1, c0, 1.0f);
    // residual partial sums
    k_resid_sums<<<dim3(N0 / 16, N0 / 16), blk, 0, stream>>>(f0, u0, pT, pF, N0);
    // final reduce + res
    k_final<<<1, 256, 0, stream>>>(pT, pF, 65536, res);
}

// Round 2
// 155.295 us; speedup vs baseline: 2.1822x; 2.1822x over previous
//
#include <hip/hip_runtime.h>

#define N0 4096
#define N1 2048
#define N2 1024

// ================= restrict: fc = restrict(f + 0.2*L(f)) =================
// coarse tile 16x16 per block (256 thr), fine tile 32x32 + halo1 in LDS
__global__ __launch_bounds__(256) void k_res_restrict(const float* __restrict__ f,
                                                      float* __restrict__ fc,
                                                      int n, int nc) {
    __shared__ float sf[34][35];
    const int by0 = blockIdx.y * 32, bx0 = blockIdx.x * 32;  // fine-grid origin
    const int tid = threadIdx.x;
    for (int idx = tid; idx < 34 * 34; idx += 256) {
        int ly = idx / 34, lx = idx - ly * 34;
        int gy = by0 - 1 + ly, gx = bx0 - 1 + lx;
        float v = 0.0f;
        if ((unsigned)gy < (unsigned)n && (unsigned)gx < (unsigned)n)
            v = f[(size_t)gy * n + gx];
        sf[ly][lx] = v;
    }
    __syncthreads();

    const int tx = tid & 15, ty = tid >> 4;
    const int a = blockIdx.y * 16 + ty, b = blockIdx.x * 16 + tx;  // coarse coords
    if (a >= nc || b >= nc) return;

    auto r_at = [&](int ly, int lx, int gy, int gx) -> float {
        float c = sf[ly][lx];
        if (gy == 0 || gy == n - 1 || gx == 0 || gx == n - 1) return c;
        return c + 0.2f * (sf[ly - 1][lx] + sf[ly + 1][lx] +
                           sf[ly][lx - 1] + sf[ly][lx + 1] - 4.0f * c);
    };
    int ly = 2 * ty + 1, lx = 2 * tx + 1;   // local coords of fine (2a,2b)
    int gy = 2 * a,      gx = 2 * b;
    float v = r_at(ly,     lx,     gy,     gx)
            + r_at(ly,     lx + 1, gy,     gx + 1)
            + r_at(ly + 1, lx,     gy + 1, gx)
            + r_at(ly + 1, lx + 1, gy + 1, gx + 1);
    fc[(size_t)a * nc + b] = 0.25f * v;
}

// ====== fused: u = jacobi(cf*f + cs*prolong(uc), f), optional residual ======
// 32x32 outputs/block, 256 threads. LDS: v,f on 36x36 (halo2), u on 34x34 (halo1).
template <bool RESID>
__global__ __launch_bounds__(256) void k_correct_smooth(
        const float* __restrict__ f, const float* __restrict__ uc,
        float* __restrict__ u, int n, int m, float cf, float cs,
        double* __restrict__ pT, double* __restrict__ pF) {
    __shared__ __align__(16) float sv[36][37];
    __shared__ float sf[36][37];
    __shared__ float su[34][35];
    const int by0 = blockIdx.y * 32, bx0 = blockIdx.x * 32;
    const int tid = threadIdx.x;

    // phase 1: v = cf*f + cs*prolong(uc) on the 36x36 halo tile (once per point)
    for (int idx = tid; idx < 36 * 36; idx += 256) {
        int ly = idx / 36, lx = idx - ly * 36;
        int gy = by0 - 2 + ly, gx = bx0 - 2 + lx;
        float fv = 0.0f, vv = 0.0f;
        if ((unsigned)gy < (unsigned)n && (unsigned)gx < (unsigned)n) {
            fv = f[(size_t)gy * n + gx];
            vv = cf * fv;
            if (gy > 0 && gy < n - 1 && gx > 0 && gx < n - 1) {
                int a0, a1, b0, b1; float wr0, wr1, wc0, wc1;
                if (gy & 1) { a0 = gy >> 1; a1 = a0 + 1; wr0 = 1.5f; wr1 = 0.5f; }
                else        { a1 = gy >> 1; a0 = a1 - 1; wr0 = 0.5f; wr1 = 1.5f; }
                if (gx & 1) { b0 = gx >> 1; b1 = b0 + 1; wc0 = 1.5f; wc1 = 0.5f; }
                else        { b1 = gx >> 1; b0 = b1 - 1; wc0 = 0.5f; wc1 = 1.5f; }
                float p = wr0 * (wc0 * uc[(size_t)a0 * m + b0] + wc1 * uc[(size_t)a0 * m + b1])
                        + wr1 * (wc0 * uc[(size_t)a1 * m + b0] + wc1 * uc[(size_t)a1 * m + b1]);
                vv += cs * p;
            }
        }
        sf[ly][lx] = fv;
        sv[ly][lx] = vv;
    }
    __syncthreads();

    // phase 2: u = v + cf*f (+ 0.2*L(v) interior) on 34x34 halo-1 tile
    for (int idx = tid; idx < 34 * 34; idx += 256) {
        int ly = idx / 34, lx = idx - ly * 34;        // su coords; sv/sf = +1
        int gy = by0 - 1 + ly, gx = bx0 - 1 + lx;
        float vc = sv[ly + 1][lx + 1];
        float uu = vc + cf * sf[ly + 1][lx + 1];
        if (gy > 0 && gy < n - 1 && gx > 0 && gx < n - 1)
            uu += 0.2f * (sv[ly][lx + 1] + sv[ly + 2][lx + 1] +
                          sv[ly + 1][lx] + sv[ly + 1][lx + 2] - 4.0f * vc);
        su[ly][lx] = uu;
    }
    __syncthreads();

    // phase 3: write u; optionally accumulate |f - A(u)| and |f|
    const int tx = tid & 31, ty = tid >> 5;
    double tT = 0.0, tF = 0.0;
    const float n2 = (float)n * (float)n;
    #pragma unroll
    for (int k = 0; k < 4; ++k) {
        int oy = ty * 4 + k;
        int gy = by0 + oy, gx = bx0 + tx;
        float uu = su[oy + 1][tx + 1];
        u[(size_t)gy * n + gx] = uu;
        if (RESID) {
            float fij = sf[oy + 2][tx + 2];
            float t;
            if (gy == 0 || gy == n - 1 || gx == 0 || gx == n - 1) {
                t = fabsf(fij);
            } else {
                float L = su[oy][tx + 1] + su[oy + 2][tx + 1] +
                          su[oy + 1][tx] + su[oy + 1][tx + 2] - 4.0f * uu;
                t = fabsf(fij - n2 * L);
            }
            tT += (double)t;
            tF += (double)fabsf(fij);
        }
    }
    if (RESID) {
        __syncthreads();                       // sv reads done (phase 2); safe to reuse
        double* sT = (double*)&sv[0][0];       // 2048 B
        double* sF = sT + 256;                 // 2048 B  (sv is 5328 B total)
        sT[tid] = tT; sF[tid] = tF;
        __syncthreads();
        for (int s = 128; s > 0; s >>= 1) {
            if (tid < s) { sT[tid] += sT[tid + s]; sF[tid] += sF[tid + s]; }
            __syncthreads();
        }
        if (tid == 0) {
            int bid = blockIdx.y * gridDim.x + blockIdx.x;
            pT[bid] = sT[0];
            pF[bid] = sF[0];
        }
    }
}

__global__ void k_final(const double* __restrict__ pT, const double* __restrict__ pF,
                        int nb, float* __restrict__ out_res) {
    __shared__ double sT[256], sF[256];
    double tT = 0.0, tF = 0.0;
    for (int i = threadIdx.x; i < nb; i += 256) { tT += pT[i]; tF += pF[i]; }
    sT[threadIdx.x] = tT; sF[threadIdx.x] = tF;
    __syncthreads();
    for (int s = 128; s > 0; s >>= 1) {
        if (threadIdx.x < s) { sT[threadIdx.x] += sT[threadIdx.x + s]; sF[threadIdx.x] += sF[threadIdx.x + s]; }
        __syncthreads();
    }
    if (threadIdx.x == 0) *out_res = (float)(sT[0] / sF[0]);
}

extern "C" void kernel_launch(void* const* d_in, const int* in_sizes, int n_in,
                              void* d_out, int out_size, void* d_ws, size_t ws_size,
                              hipStream_t stream) {
    const float* f0 = (const float*)d_in[0];
    float* u0  = (float*)d_out;                      // N0*N0 floats
    float* res = u0 + (size_t)N0 * N0;               // scalar

    char* ws = (char*)d_ws;
    float* f1 = (float*)ws;                                           // N1*N1
    float* u1 = (float*)(ws + (size_t)N1 * N1 * 4);                   // N1*N1
    float* f2 = (float*)(ws + (size_t)2 * N1 * N1 * 4);               // N2*N2
    double* pT = (double*)(ws + (size_t)2 * N1 * N1 * 4 + (size_t)N2 * N2 * 4);
    const int NB = (N0 / 32) * (N0 / 32);            // 16384 partial pairs
    double* pF = pT + NB;

    const float c0 = -0.2f / ((float)N0 * (float)N0);
    const float c1 = -0.2f / ((float)N1 * (float)N1);
    const float c2 = -0.2f / ((float)N2 * (float)N2);

    // level 0 -> f1   (coarse tile 16 => grid nc/16)
    k_res_restrict<<<dim3(N1 / 16, N1 / 16), 256, 0, stream>>>(f0, f1, N0, N1);
    // level 1 -> f2
    k_res_restrict<<<dim3(N2 / 16, N2 / 16), 256, 0, stream>>>(f1, f2, N1, N2);
    // u1 = jacobi(c1*f1 + prolong(c2*f2), f1)
    k_correct_smooth<false><<<dim3(N1 / 32, N1 / 32), 256, 0, stream>>>(
        f1, f2, u1, N1, N2, c1, c2, nullptr, nullptr);
    // u0 = jacobi(c0*f0 + prolong(u1), f0), fused residual partials
    k_correct_smooth<true><<<dim3(N0 / 32, N0 / 32), 256, 0, stream>>>(
        f0, u1, u0, N0, N1, c0, 1.0f, pT, pF);
    // final reduce -> res
    k_final<<<1, 256, 0, stream>>>(pT, pF, NB, res);
}

// Round 3
// 146.681 us; speedup vs baseline: 2.3104x; 1.0587x over previous
//
#include <hip/hip_runtime.h>

#define N0 4096
#define N1 2048
#define N2 1024

// ============ restrict: fc = restrict(f + 0.2*L(f)), coarse 16x16/block ============
__global__ __launch_bounds__(256) void k_res_restrict(const float* __restrict__ f,
                                                      float* __restrict__ fc,
                                                      int n, int nc) {
    __shared__ __align__(16) float sf[34][40];
    const int tid = threadIdx.x;
    const int fy0 = blockIdx.y * 32, fx0 = blockIdx.x * 32;   // fine origin
    const bool edge = (blockIdx.x == 0) | (blockIdx.y == 0) |
                      (blockIdx.x == gridDim.x - 1) | (blockIdx.y == gridDim.y - 1);
    const int tx = tid & 15, ty = tid >> 4;
    const int a = blockIdx.y * 16 + ty, b = blockIdx.x * 16 + tx;

    if (!edge) {
        // stage fine rows fy0-1..fy0+32, cols fx0-4..fx0+35 (aligned float4)
        for (int idx = tid; idx < 340; idx += 256) {
            int r = idx / 10, c4 = idx - r * 10;
            ((float4*)sf[r])[c4] =
                ((const float4*)(f + (size_t)(fy0 - 1 + r) * n + (fx0 - 4)))[c4];
        }
        __syncthreads();
        // sum over quad r-values = 0.6*Sq + 0.2*Sring  ->  *0.25
        float q = sf[2*ty+1][2*tx+4] + sf[2*ty+1][2*tx+5]
                + sf[2*ty+2][2*tx+4] + sf[2*ty+2][2*tx+5];
        float ring = sf[2*ty  ][2*tx+4] + sf[2*ty  ][2*tx+5]
                   + sf[2*ty+3][2*tx+4] + sf[2*ty+3][2*tx+5]
                   + sf[2*ty+1][2*tx+3] + sf[2*ty+2][2*tx+3]
                   + sf[2*ty+1][2*tx+6] + sf[2*ty+2][2*tx+6];
        fc[(size_t)a * nc + b] = 0.15f * q + 0.05f * ring;
    } else {
        for (int idx = tid; idx < 34 * 40; idx += 256) {
            int r = idx / 40, sx = idx - r * 40;
            int gy = fy0 - 1 + r, gx = fx0 - 4 + sx;
            float v = 0.0f;
            if ((unsigned)gy < (unsigned)n && (unsigned)gx < (unsigned)n)
                v = f[(size_t)gy * n + gx];
            sf[r][sx] = v;
        }
        __syncthreads();
        auto r_at = [&](int lr, int lc, int gy, int gx) -> float {
            float c = sf[lr][lc];
            if (gy == 0 || gy == n - 1 || gx == 0 || gx == n - 1) return c;
            return c + 0.2f * (sf[lr-1][lc] + sf[lr+1][lc] +
                               sf[lr][lc-1] + sf[lr][lc+1] - 4.0f * c);
        };
        int lr = 2 * ty + 1, lc = 2 * tx + 4, gy = 2 * a, gx = 2 * b;
        float v = r_at(lr,   lc,   gy,   gx) + r_at(lr,   lc+1, gy,   gx+1)
                + r_at(lr+1, lc,   gy+1, gx) + r_at(lr+1, lc+1, gy+1, gx+1);
        fc[(size_t)a * nc + b] = 0.25f * v;
    }
}

// ====== fused: u = jacobi(cf*f + cs*prolong(uc), f), optional residual ======
// 32x32 outputs/block, 256 threads.
template <bool RESID>
__global__ __launch_bounds__(256) void k_correct_smooth(
        const float* __restrict__ f, const float* __restrict__ uc,
        float* __restrict__ u, int n, int m, float cf, float cs,
        double* __restrict__ pT, double* __restrict__ pF) {
    __shared__ __align__(16) float sf[36][40];   // f: rows by0-2.., cols bx0-4..
    __shared__ __align__(16) float sv[36][40];   // v: rows by0-2.., cols bx0-2.. (cols 0..35)
    __shared__ __align__(16) float su[34][40];   // u: rows by0-1.., cols bx0-1.. (cols 0..33)
    __shared__ __align__(16) float suc[20][24];  // cs*uc: rows by0/2-2.., cols bx0/2-4..

    const int tid = threadIdx.x;
    const int by0 = blockIdx.y * 32, bx0 = blockIdx.x * 32;
    const bool edge = (blockIdx.x == 0) | (blockIdx.y == 0) |
                      (blockIdx.x == gridDim.x - 1) | (blockIdx.y == gridDim.y - 1);

    if (!edge) {
        // ---------- fast path (branch-free) ----------
        for (int idx = tid; idx < 360; idx += 256) {          // f tile, float4
            int r = idx / 10, c4 = idx - r * 10;
            ((float4*)sf[r])[c4] =
                ((const float4*)(f + (size_t)(by0 - 2 + r) * n + (bx0 - 4)))[c4];
        }
        for (int idx = tid; idx < 120; idx += 256) {          // uc tile, float4, pre-scaled
            int r = idx / 6, c4 = idx - r * 6;
            float4 v = ((const float4*)(uc + (size_t)(by0/2 - 2 + r) * m + (bx0/2 - 4)))[c4];
            v.x *= cs; v.y *= cs; v.z *= cs; v.w *= cs;
            ((float4*)suc[r])[c4] = v;
        }
        __syncthreads();
        // B: v = cf*f + prolong(cs*uc) on 36x36 via 18x18 separable quads
        for (int idx = tid; idx < 324; idx += 256) {
            int qr = idx / 18, qc = idx - qr * 18;
            float h0[3], h1[3];
            #pragma unroll
            for (int i = 0; i < 3; ++i) {
                float u0v = suc[qr + i][qc + 2];
                float u1v = suc[qr + i][qc + 3];
                float u2v = suc[qr + i][qc + 4];
                h0[i] = 0.5f * u0v + 1.5f * u1v;
                h1[i] = 1.5f * u1v + 0.5f * u2v;
            }
            float2 top, bot;
            top.x = 0.5f*h0[0] + 1.5f*h0[1] + cf * sf[2*qr  ][2*qc+2];
            top.y = 0.5f*h1[0] + 1.5f*h1[1] + cf * sf[2*qr  ][2*qc+3];
            bot.x = 1.5f*h0[1] + 0.5f*h0[2] + cf * sf[2*qr+1][2*qc+2];
            bot.y = 1.5f*h1[1] + 0.5f*h1[2] + cf * sf[2*qr+1][2*qc+3];
            *(float2*)&sv[2*qr  ][2*qc] = top;
            *(float2*)&sv[2*qr+1][2*qc] = bot;
        }
        __syncthreads();
        // C: u = v + cf*f + 0.2*L(v) on 34x34
        for (int idx = tid; idx < 1156; idx += 256) {
            int r = idx / 34, c = idx - r * 34;
            float vc = sv[r + 1][c + 1];
            su[r][c] = vc + cf * sf[r + 1][c + 3]
                     + 0.2f * (sv[r][c + 1] + sv[r + 2][c + 1] +
                               sv[r + 1][c] + sv[r + 1][c + 2] - 4.0f * vc);
        }
        __syncthreads();
    } else {
        // ---------- slow path (guarded, edge blocks only) ----------
        for (int idx = tid; idx < 36 * 40; idx += 256) {
            int r = idx / 40, sx = idx - r * 40;
            int gy = by0 - 2 + r, gx = bx0 - 4 + sx;
            float fv = 0.0f;
            if ((unsigned)gy < (unsigned)n && (unsigned)gx < (unsigned)n)
                fv = f[(size_t)gy * n + gx];
            sf[r][sx] = fv;
        }
        __syncthreads();
        for (int idx = tid; idx < 36 * 36; idx += 256) {
            int r = idx / 36, c = idx - r * 36;
            int gy = by0 - 2 + r, gx = bx0 - 2 + c;
            float vv = 0.0f;
            if ((unsigned)gy < (unsigned)n && (unsigned)gx < (unsigned)n) {
                vv = cf * sf[r][c + 2];
                if (gy > 0 && gy < n - 1 && gx > 0 && gx < n - 1) {
                    int a0, a1, b0, b1; float wr0, wr1, wc0, wc1;
                    if (gy & 1) { a0 = gy >> 1; a1 = a0 + 1; wr0 = 1.5f; wr1 = 0.5f; }
                    else        { a1 = gy >> 1; a0 = a1 - 1; wr0 = 0.5f; wr1 = 1.5f; }
                    if (gx & 1) { b0 = gx >> 1; b1 = b0 + 1; wc0 = 1.5f; wc1 = 0.5f; }
                    else        { b1 = gx >> 1; b0 = b1 - 1; wc0 = 0.5f; wc1 = 1.5f; }
                    float p = wr0 * (wc0 * uc[(size_t)a0*m + b0] + wc1 * uc[(size_t)a0*m + b1])
                            + wr1 * (wc0 * uc[(size_t)a1*m + b0] + wc1 * uc[(size_t)a1*m + b1]);
                    vv += cs * p;
                }
            }
            sv[r][c] = vv;
        }
        __syncthreads();
        for (int idx = tid; idx < 34 * 34; idx += 256) {
            int r = idx / 34, c = idx - r * 34;
            int gy = by0 - 1 + r, gx = bx0 - 1 + c;
            if ((unsigned)gy < (unsigned)n && (unsigned)gx < (unsigned)n) {
                float vc = sv[r + 1][c + 1];
                float uu = vc + cf * sf[r + 1][c + 3];
                if (gy > 0 && gy < n - 1 && gx > 0 && gx < n - 1)
                    uu += 0.2f * (sv[r][c + 1] + sv[r + 2][c + 1] +
                                  sv[r + 1][c] + sv[r + 1][c + 2] - 4.0f * vc);
                su[r][c] = uu;
            }
        }
        __syncthreads();
    }

    // D: write u (float4), optional fused residual partials
    const int tx = tid & 7, ty = tid >> 3;
    const int gy = by0 + ty, gx0 = bx0 + 4 * tx;
    float4 uvec = make_float4(su[ty + 1][4*tx + 1], su[ty + 1][4*tx + 2],
                              su[ty + 1][4*tx + 3], su[ty + 1][4*tx + 4]);
    *(float4*)(u + (size_t)gy * n + gx0) = uvec;

    if (RESID) {
        const float n2 = (float)n * (float)n;
        float tT = 0.0f, tF = 0.0f;
        #pragma unroll
        for (int j = 0; j < 4; ++j) {
            int gx = gx0 + j;
            int c = 4 * tx + 1 + j;                 // su col of this point
            float fij = sf[ty + 2][4 * tx + 4 + j];
            float uuc = (&uvec.x)[j];
            float t;
            if (edge && (gy == 0 || gy == n - 1 || gx == 0 || gx == n - 1)) {
                t = fabsf(fij);
            } else {
                float L = su[ty][c] + su[ty + 2][c] +
                          su[ty + 1][c - 1] + su[ty + 1][c + 1] - 4.0f * uuc;
                t = fabsf(fij - n2 * L);
            }
            tT += t;
            tF += fabsf(fij);
        }
        double* sT = (double*)&sv[0][0];
        double* sF = sT + 256;
        sT[tid] = (double)tT; sF[tid] = (double)tF;
        __syncthreads();
        for (int s = 128; s > 0; s >>= 1) {
            if (tid < s) { sT[tid] += sT[tid + s]; sF[tid] += sF[tid + s]; }
            __syncthreads();
        }
        if (tid == 0) {
            int bid = blockIdx.y * gridDim.x + blockIdx.x;
            pT[bid] = sT[0];
            pF[bid] = sF[0];
        }
    }
}

__global__ void k_final(const double* __restrict__ pT, const double* __restrict__ pF,
                        int nb, float* __restrict__ out_res) {
    __shared__ double sT[256], sF[256];
    double tT = 0.0, tF = 0.0;
    for (int i = threadIdx.x; i < nb; i += 256) { tT += pT[i]; tF += pF[i]; }
    sT[threadIdx.x] = tT; sF[threadIdx.x] = tF;
    __syncthreads();
    for (int s = 128; s > 0; s >>= 1) {
        if (threadIdx.x < s) { sT[threadIdx.x] += sT[threadIdx.x + s]; sF[threadIdx.x] += sF[threadIdx.x + s]; }
        __syncthreads();
    }
    if (threadIdx.x == 0) *out_res = (float)(sT[0] / sF[0]);
}

extern "C" void kernel_launch(void* const* d_in, const int* in_sizes, int n_in,
                              void* d_out, int out_size, void* d_ws, size_t ws_size,
                              hipStream_t stream) {
    const float* f0 = (const float*)d_in[0];
    float* u0  = (float*)d_out;                      // N0*N0 floats
    float* res = u0 + (size_t)N0 * N0;               // scalar

    char* ws = (char*)d_ws;
    float* f1 = (float*)ws;                                           // N1*N1
    float* u1 = (float*)(ws + (size_t)N1 * N1 * 4);                   // N1*N1
    float* f2 = (float*)(ws + (size_t)2 * N1 * N1 * 4);               // N2*N2
    double* pT = (double*)(ws + (size_t)2 * N1 * N1 * 4 + (size_t)N2 * N2 * 4);
    const int NB = (N0 / 32) * (N0 / 32);            // 16384 partial pairs
    double* pF = pT + NB;

    const float c0 = -0.2f / ((float)N0 * (float)N0);
    const float c1 = -0.2f / ((float)N1 * (float)N1);
    const float c2 = -0.2f / ((float)N2 * (float)N2);

    k_res_restrict<<<dim3(N1 / 16, N1 / 16), 256, 0, stream>>>(f0, f1, N0, N1);
    k_res_restrict<<<dim3(N2 / 16, N2 / 16), 256, 0, stream>>>(f1, f2, N1, N2);
    k_correct_smooth<false><<<dim3(N1 / 32, N1 / 32), 256, 0, stream>>>(
        f1, f2, u1, N1, N2, c1, c2, nullptr, nullptr);
    k_correct_smooth<true><<<dim3(N0 / 32, N0 / 32), 256, 0, stream>>>(
        f0, u1, u0, N0, N1, c0, 1.0f, pT, pF);
    k_final<<<1, 256, 0, stream>>>(pT, pF, NB, res);
}